// Round 3
// baseline (210.883 us; speedup 1.0000x reference)
//
#include <hip/hip_runtime.h>
#include <hip/hip_bf16.h>

typedef __attribute__((ext_vector_type(8))) short short8;
typedef __attribute__((ext_vector_type(4))) short short4v;
typedef __attribute__((ext_vector_type(4))) float floatx4;

#define BDIM 128
#define RDIM 1024
#define NB   4096
#define NG   16
#define LDP  66     // LDS row stride in shorts (132 B): bank-clean with XOR swizzle

__device__ __forceinline__ float mishf(float x) {
    float e = __expf(x);
    float t = e * (e + 2.0f);
    float r = x * (t / (t + 2.0f));
    return x > 20.0f ? x : r;
}

__device__ __forceinline__ short8 cvt8v(float4 f0, float4 f1) {
    union { __hip_bfloat162 h; unsigned u; } c0, c1, c2, c3;
    c0.h = __float22bfloat162_rn(make_float2(f0.x, f0.y));
    c1.h = __float22bfloat162_rn(make_float2(f0.z, f0.w));
    c2.h = __float22bfloat162_rn(make_float2(f1.x, f1.y));
    c3.h = __float22bfloat162_rn(make_float2(f1.z, f1.w));
    union { short8 s; unsigned u[4]; } r;
    r.u[0] = c0.u; r.u[1] = c1.u; r.u[2] = c2.u; r.u[3] = c3.u;
    return r.s;
}

__device__ __forceinline__ short4v cvt4v(float4 f) {
    union { __hip_bfloat162 h; unsigned u; } c0, c1;
    c0.h = __float22bfloat162_rn(make_float2(f.x, f.y));
    c1.h = __float22bfloat162_rn(make_float2(f.z, f.w));
    union { short4v s; unsigned u[2]; } r;
    r.u[0] = c0.u; r.u[1] = c1.u;
    return r.s;
}

// async global->LDS, 16B per lane, LDS dest = wave-uniform base + lane*16
__device__ __forceinline__ void gld16(const void* g, void* l) {
    __builtin_amdgcn_global_load_lds(
        (const __attribute__((address_space(1))) unsigned int*)g,
        (__attribute__((address_space(3))) unsigned int*)l, 16, 0, 0);
}

#define MFMA(a, b, c) __builtin_amdgcn_mfma_f32_16x16x32_bf16(a, b, c, 0, 0, 0)

// region boundaries (floats) for the flat conversion pass
#define C1       4194304u   // RF 4096*1024
#define C2       5242880u   // +Wrfrf 1024*1024
#define C3       5373952u   // +Wrfbb 128*1024
#define C4       5505024u   // +Wbbrf 1024*128
#define CT       5521408u   // +Wbbbb 128*128
#define FLATB    1536

// ---------------- prep: BB mean + one-time fp32->bf16 of all GEMM operands ----------------
__global__ void __launch_bounds__(256) k_prep(
    const float* __restrict__ bb, const float* __restrict__ rf,
    const float* __restrict__ Wrfrf, const float* __restrict__ Wrfbb,
    const float* __restrict__ Wbbrf, const float* __restrict__ Wbbbb,
    short* __restrict__ bb_b, short* __restrict__ mean_b, short* __restrict__ rf_b,
    short* __restrict__ wrfrf_b, short* __restrict__ wrfbb_b,
    short* __restrict__ wbbrf_b, short* __restrict__ wbbbb_b)
{
    int bid = blockIdx.x;
    int tid = threadIdx.x;
    if (bid < 512) {
        // mean over G + bf16 copy of BB
        int b = bid * 8 + (tid >> 5);
        int d = (tid & 31) * 4;
        const float4* p = (const float4*)(bb + (size_t)b * (NG * BDIM) + d);
        short* ob = bb_b + (size_t)b * (NG * BDIM) + d;
        float4 s = {0.f, 0.f, 0.f, 0.f};
        #pragma unroll
        for (int g = 0; g < NG; ++g) {
            float4 v = p[g * (BDIM / 4)];
            s.x += v.x; s.y += v.y; s.z += v.z; s.w += v.w;
            *(short4v*)(ob + g * BDIM) = cvt4v(v);
        }
        s.x *= 0.0625f; s.y *= 0.0625f; s.z *= 0.0625f; s.w *= 0.0625f;
        *(short4v*)(mean_b + (size_t)b * BDIM + d) = cvt4v(s);
    } else {
        // flat fp32->bf16 over RF + 4 weights (all region sizes multiples of 8)
        size_t t = (size_t)(bid - 512) * 256 + tid;
        for (size_t base = t * 8; base < CT; base += (size_t)FLATB * 256 * 8) {
            const float* s; short* dst; size_t off;
            if (base < C1)      { s = rf;    dst = rf_b;    off = base; }
            else if (base < C2) { s = Wrfrf; dst = wrfrf_b; off = base - C1; }
            else if (base < C3) { s = Wrfbb; dst = wrfbb_b; off = base - C2; }
            else if (base < C4) { s = Wbbrf; dst = wbbrf_b; off = base - C3; }
            else                { s = Wbbbb; dst = wbbbb_b; off = base - C4; }
            float4 f0 = ((const float4*)(s + off))[0];
            float4 f1 = ((const float4*)(s + off))[1];
            *(short8*)(dst + off) = cvt8v(f0, f1);
        }
    }
}

// ---- new_RF = mish(RF@Wrfrf^T+b1) + mish(mean@Wbbrf^T+b2); rf2bb = mish(RF@Wrfbb^T+b3) ----
// Merged B-panel: Wrfrf(1024 rows) ++ Wrfbb(128 rows) = 1152 N-cols. Grid 32x18 = 576.
// Tile 128(M)x64(N), BK=64, reg-staged 2-deep pipeline (loads for it+2 issued at it):
// register loads stay in flight across __syncthreads (no vmcnt drain at barrier).
__global__ void __launch_bounds__(256) k_newrf(
    const short* __restrict__ rfb,     // [4096,1024] bf16
    const short* __restrict__ meanb,   // [4096,128]  bf16
    const short* __restrict__ wrfrfb,  // [1024,1024] bf16
    const float* __restrict__ brfrf,
    const short* __restrict__ wbbrfb,  // [1024,128]  bf16
    const float* __restrict__ bbbrf,
    const short* __restrict__ wrfbbb,  // [128,1024]  bf16
    const float* __restrict__ brfbb,
    float* __restrict__ out,           // [4096,1024]
    float* __restrict__ rf2bb)         // [4096,128] fp32 ws
{
    __shared__ alignas(16) short As[2][128 * LDP];
    __shared__ alignas(16) short Bs[2][64 * LDP];
    int tid = threadIdx.x;
    int wave = tid >> 6, lane = tid & 63;
    int r = lane & 15, quad = lane >> 4;
    int wm = (wave & 1) * 64, wn = (wave >> 1) * 32;
    int bid = blockIdx.x;
    int nt = bid % 18, mt = bid / 18;
    int m0 = mt * 128;
    bool isP = (nt >= 16);
    const short* Bsrc = isP ? (wrfbbb + (size_t)(nt - 16) * 64 * RDIM)
                            : (wrfrfb + (size_t)nt * 64 * RDIM);

    // staging thread map: srow 0..31, sslot 0..7; consecutive tids -> consecutive 16B (coalesced)
    int srow = tid >> 3;
    int sslot = tid & 7;
    int wsl = ((sslot ^ (srow & 7)) << 3);       // XOR-swizzled K-slot (write side)
    int soff = srow * LDP + wsl;

    const short* aG = rfb + (size_t)(m0 + srow) * RDIM + sslot * 8;
    const short* bG = Bsrc + (size_t)srow * RDIM + sslot * 8;

    floatx4 acc1[4][2], acc2[4][2];
    #pragma unroll
    for (int mi = 0; mi < 4; ++mi) {
        acc1[mi][0] = floatx4{0.f,0.f,0.f,0.f}; acc1[mi][1] = acc1[mi][0];
        acc2[mi][0] = acc1[mi][0]; acc2[mi][1] = acc1[mi][0];
    }

    short8 ar[4], br[2];
    auto gload = [&](int k) {
        #pragma unroll
        for (int j = 0; j < 4; ++j) ar[j] = *(const short8*)(aG + (size_t)j * 32 * RDIM + k);
        #pragma unroll
        for (int j = 0; j < 2; ++j) br[j] = *(const short8*)(bG + (size_t)j * 32 * RDIM + k);
    };
    auto lwrite = [&](int buf) {
        #pragma unroll
        for (int j = 0; j < 4; ++j) *(short8*)&As[buf][j * 32 * LDP + soff] = ar[j];
        #pragma unroll
        for (int j = 0; j < 2; ++j) *(short8*)&Bs[buf][j * 32 * LDP + soff] = br[j];
    };
    auto compute_tile = [&](const short* Ac, const short* Bc, floatx4 (&acc)[4][2]) {
        #pragma unroll
        for (int kk = 0; kk < 2; ++kk) {
            int sw = (((kk << 2) + quad) ^ (r & 7)) << 3;
            short8 af[4];
            #pragma unroll
            for (int mi = 0; mi < 4; ++mi)
                af[mi] = *(const short8*)&Ac[(wm + mi * 16 + r) * LDP + sw];
            short8 bf0 = *(const short8*)&Bc[(wn + r) * LDP + sw];
            short8 bf1 = *(const short8*)&Bc[(wn + 16 + r) * LDP + sw];
            #pragma unroll
            for (int mi = 0; mi < 4; ++mi) {
                acc[mi][0] = MFMA(af[mi], bf0, acc[mi][0]);
                acc[mi][1] = MFMA(af[mi], bf1, acc[mi][1]);
            }
        }
    };

    // prologue: tile0 -> buf0; tile1 loads in flight
    gload(0);
    lwrite(0);
    gload(64);
    __syncthreads();

    for (int it = 0; it < 16; ++it) {
        int buf = it & 1;
        compute_tile(As[buf], Bs[buf], acc1);
        if (it < 15) lwrite(buf ^ 1);       // regs hold tile it+1
        if (it < 14) gload((it + 2) * 64);  // issue tile it+2 (in flight across barrier)
        __syncthreads();
    }

    // ---- GEMM2: mean @ Wbbrf^T, K=128 (2 tiles of BK=64), only for nt<16 ----
    if (!isP) {
        const short* a2G = meanb  + (size_t)(m0 + srow) * BDIM + sslot * 8;
        const short* b2G = wbbrfb + (size_t)(nt * 64 + srow) * BDIM + sslot * 8;
        #pragma unroll
        for (int j = 0; j < 4; ++j) ar[j] = *(const short8*)(a2G + (size_t)j * 32 * BDIM);
        #pragma unroll
        for (int j = 0; j < 2; ++j) br[j] = *(const short8*)(b2G + (size_t)j * 32 * BDIM);
        lwrite(0);
        #pragma unroll
        for (int j = 0; j < 4; ++j) ar[j] = *(const short8*)(a2G + (size_t)j * 32 * BDIM + 64);
        #pragma unroll
        for (int j = 0; j < 2; ++j) br[j] = *(const short8*)(b2G + (size_t)j * 32 * BDIM + 64);
        __syncthreads();
        compute_tile(As[0], Bs[0], acc2);
        lwrite(1);
        __syncthreads();
        compute_tile(As[1], Bs[1], acc2);
    }

    // ---- epilogue ----
    if (!isP) {
        #pragma unroll
        for (int nj = 0; nj < 2; ++nj) {
            int col = nt * 64 + wn + nj * 16 + r;
            float b1 = brfrf[col];
            float b2 = bbbrf[col];
            #pragma unroll
            for (int mi = 0; mi < 4; ++mi) {
                #pragma unroll
                for (int g = 0; g < 4; ++g) {
                    int row = m0 + wm + mi * 16 + quad * 4 + g;
                    out[(size_t)row * RDIM + col] =
                        mishf(acc1[mi][nj][g] + b1) + mishf(acc2[mi][nj][g] + b2);
                }
            }
        }
    } else {
        #pragma unroll
        for (int nj = 0; nj < 2; ++nj) {
            int colL = (nt - 16) * 64 + wn + nj * 16 + r;
            float bs = brfbb[colL];
            #pragma unroll
            for (int mi = 0; mi < 4; ++mi) {
                #pragma unroll
                for (int g = 0; g < 4; ++g) {
                    int row = m0 + wm + mi * 16 + quad * 4 + g;
                    rf2bb[(size_t)row * BDIM + colL] = mishf(acc1[mi][nj][g] + bs);
                }
            }
        }
    }
}

// ---------------- new_BB = mish(BB @ W_bbbb^T + b) + rf2bb[b] ----------------
// W (32KB) staged once via gld16 (pre-swizzled source, 0-conflict reads);
// A-tile loaded DIRECTLY global->VGPR fragments (no LDS staging, single barrier).
__global__ void __launch_bounds__(256) k_newbb(
    const short* __restrict__ bbb,   // [65536,128] bf16
    const short* __restrict__ wb,    // [128,128]   bf16
    const float* __restrict__ bias,  // [128]
    const float* __restrict__ rf2bb, // [4096,128]  fp32
    float* __restrict__ out)         // [65536,128]
{
    __shared__ alignas(16) short Wt[128 * 128];
    int tid = threadIdx.x;
    int wave = tid >> 6, lane = tid & 63;
    int r = lane & 15, quad = lane >> 4;
    size_t m0 = (size_t)blockIdx.x * 128;

    // stage W: 1 issue = 64 lanes x 16B = 4 rows of 256B; source column pre-swizzled
    int lrow = lane >> 4;
    int lslot = lane & 15;
    #pragma unroll
    for (int j = 0; j < 8; ++j) {
        int row = wave * 32 + j * 4 + lrow;
        int col = ((lslot ^ (row & 7)) << 3);
        gld16(wb + (size_t)row * BDIM + col, &Wt[(wave * 32 + j * 4) * 128]);
    }

    // A fragments direct from global (linear, no swizzle): row wave*32+mi*16+r, K kc*32+quad*8
    const short* aB = bbb + (m0 + wave * 32 + r) * BDIM + quad * 8;
    short8 afr[2][4];
    #pragma unroll
    for (int mi = 0; mi < 2; ++mi)
        #pragma unroll
        for (int kc = 0; kc < 4; ++kc)
            afr[mi][kc] = *(const short8*)(aB + mi * 16 * BDIM + kc * 32);

    floatx4 acc[2][8];
    #pragma unroll
    for (int i = 0; i < 2; ++i)
        #pragma unroll
        for (int j = 0; j < 8; ++j) acc[i][j] = floatx4{0.f,0.f,0.f,0.f};

    __syncthreads();   // drains W gld16 (and A loads) -> Wt ready

    #pragma unroll
    for (int kc = 0; kc < 4; ++kc) {
        int sw = (((kc << 2) + quad) ^ (r & 7)) << 3;
        #pragma unroll
        for (int nj = 0; nj < 8; ++nj) {
            short8 b = *(const short8*)&Wt[(nj * 16 + r) * 128 + sw];
            acc[0][nj] = MFMA(afr[0][kc], b, acc[0][nj]);
            acc[1][nj] = MFMA(afr[1][kc], b, acc[1][nj]);
        }
    }

    #pragma unroll
    for (int mi = 0; mi < 2; ++mi) {
        #pragma unroll
        for (int nj = 0; nj < 8; ++nj) {
            int col = nj * 16 + r;
            float bs = bias[col];
            #pragma unroll
            for (int g = 0; g < 4; ++g) {
                size_t row = m0 + wave * 32 + mi * 16 + quad * 4 + g;
                out[row * BDIM + col] = mishf(acc[mi][nj][g] + bs) + rf2bb[(row >> 4) * BDIM + col];
            }
        }
    }
}

extern "C" void kernel_launch(void* const* d_in, const int* in_sizes, int n_in,
                              void* d_out, int out_size, void* d_ws, size_t ws_size,
                              hipStream_t stream) {
    const float* BB    = (const float*)d_in[0];
    const float* RF    = (const float*)d_in[1];
    const float* Wrfbb = (const float*)d_in[2];
    const float* brfbb = (const float*)d_in[3];
    const float* Wrfrf = (const float*)d_in[4];
    const float* brfrf = (const float*)d_in[5];
    const float* Wbbrf = (const float*)d_in[6];
    const float* bbbrf = (const float*)d_in[7];
    const float* Wbbbb = (const float*)d_in[8];
    const float* bbbbb = (const float*)d_in[9];

    float* outBB = (float*)d_out;
    float* outRF = outBB + (size_t)NB * NG * BDIM;

    char* w = (char*)d_ws;
    short* mean_b  = (short*)(w);                  // 4096*128*2    = 1,048,576
    short* rf_b    = (short*)(w + 1048576);        // 4096*1024*2   = 8,388,608
    short* wrfrf_b = (short*)(w + 9437184);        // 1024*1024*2   = 2,097,152
    short* wrfbb_b = (short*)(w + 11534336);       // 128*1024*2    =   262,144
    short* wbbrf_b = (short*)(w + 11796480);       // 1024*128*2    =   262,144
    short* wbbbb_b = (short*)(w + 12058624);       // 128*128*2     =    32,768
    short* bb_b    = (short*)(w + 12091392);       // 65536*128*2   = 16,777,216
    float* rf2bb   = (float*)(w + 28868608);       // 4096*128*4    =  2,097,152
    // total ws: 30,965,760 B

    k_prep <<<512 + FLATB, 256, 0, stream>>>(BB, RF, Wrfrf, Wrfbb, Wbbrf, Wbbbb,
                                             bb_b, mean_b, rf_b, wrfrf_b, wrfbb_b,
                                             wbbrf_b, wbbbb_b);
    k_newrf<<<576, 256, 0, stream>>>(rf_b, mean_b, wrfrf_b, brfrf, wbbrf_b, bbbrf,
                                     wrfbb_b, brfbb, outRF, rf2bb);
    k_newbb<<<512, 256, 0, stream>>>(bb_b, wbbbb_b, bbbbb, rf2bb, outBB);
}

// Round 4
// 154.186 us; speedup vs baseline: 1.3677x; 1.3677x over previous
//
#include <hip/hip_runtime.h>
#include <hip/hip_bf16.h>

typedef __attribute__((ext_vector_type(8))) short short8;
typedef __attribute__((ext_vector_type(4))) short short4v;
typedef __attribute__((ext_vector_type(4))) float floatx4;

#define BDIM 128
#define RDIM 1024
#define NB   4096
#define NG   16
#define LDP  40     // Round-0 proven LDS stride (80 B)

__device__ __forceinline__ float mishf(float x) {
    float e = __expf(x);
    float t = e * (e + 2.0f);
    float r = x * (t / (t + 2.0f));
    return x > 20.0f ? x : r;
}

__device__ __forceinline__ short8 cvt8v(float4 f0, float4 f1) {
    union { __hip_bfloat162 h; unsigned u; } c0, c1, c2, c3;
    c0.h = __float22bfloat162_rn(make_float2(f0.x, f0.y));
    c1.h = __float22bfloat162_rn(make_float2(f0.z, f0.w));
    c2.h = __float22bfloat162_rn(make_float2(f1.x, f1.y));
    c3.h = __float22bfloat162_rn(make_float2(f1.z, f1.w));
    union { short8 s; unsigned u[4]; } r;
    r.u[0] = c0.u; r.u[1] = c1.u; r.u[2] = c2.u; r.u[3] = c3.u;
    return r.s;
}

__device__ __forceinline__ short4v cvt4v(float4 f) {
    union { __hip_bfloat162 h; unsigned u; } c0, c1;
    c0.h = __float22bfloat162_rn(make_float2(f.x, f.y));
    c1.h = __float22bfloat162_rn(make_float2(f.z, f.w));
    union { short4v s; unsigned u[2]; } r;
    r.u[0] = c0.u; r.u[1] = c1.u;
    return r.s;
}

// async global->LDS, 16B per lane, LDS dest = wave-uniform base + lane*16
__device__ __forceinline__ void gld16(const void* g, void* l) {
    __builtin_amdgcn_global_load_lds(
        (const __attribute__((address_space(1))) unsigned int*)g,
        (__attribute__((address_space(3))) unsigned int*)l, 16, 0, 0);
}

#define MFMA(a, b, c) __builtin_amdgcn_mfma_f32_16x16x32_bf16(a, b, c, 0, 0, 0)

// region boundaries (floats) for the flat conversion pass
#define C1       4194304u   // RF 4096*1024
#define C2       5242880u   // +Wrfrf 1024*1024
#define C3       5373952u   // +Wrfbb 128*1024
#define C4       5505024u   // +Wbbrf 1024*128
#define CT       5521408u   // +Wbbbb 128*128
#define FLATB    1536

// ---------------- prep: BB mean + one-time fp32->bf16 of all GEMM operands ----------------
__global__ void __launch_bounds__(256) k_prep(
    const float* __restrict__ bb, const float* __restrict__ rf,
    const float* __restrict__ Wrfrf, const float* __restrict__ Wrfbb,
    const float* __restrict__ Wbbrf, const float* __restrict__ Wbbbb,
    short* __restrict__ bb_b, short* __restrict__ mean_b, short* __restrict__ rf_b,
    short* __restrict__ wrfrf_b, short* __restrict__ wrfbb_b,
    short* __restrict__ wbbrf_b, short* __restrict__ wbbbb_b)
{
    int bid = blockIdx.x;
    int tid = threadIdx.x;
    if (bid < 512) {
        // mean over G + bf16 copy of BB
        int b = bid * 8 + (tid >> 5);
        int d = (tid & 31) * 4;
        const float4* p = (const float4*)(bb + (size_t)b * (NG * BDIM) + d);
        short* ob = bb_b + (size_t)b * (NG * BDIM) + d;
        float4 s = {0.f, 0.f, 0.f, 0.f};
        #pragma unroll
        for (int g = 0; g < NG; ++g) {
            float4 v = p[g * (BDIM / 4)];
            s.x += v.x; s.y += v.y; s.z += v.z; s.w += v.w;
            *(short4v*)(ob + g * BDIM) = cvt4v(v);
        }
        s.x *= 0.0625f; s.y *= 0.0625f; s.z *= 0.0625f; s.w *= 0.0625f;
        *(short4v*)(mean_b + (size_t)b * BDIM + d) = cvt4v(s);
    } else {
        // flat fp32->bf16 over RF + 4 weights (all region sizes multiples of 8)
        size_t t = (size_t)(bid - 512) * 256 + tid;
        for (size_t base = t * 8; base < CT; base += (size_t)FLATB * 256 * 8) {
            const float* s; short* dst; size_t off;
            if (base < C1)      { s = rf;    dst = rf_b;    off = base; }
            else if (base < C2) { s = Wrfrf; dst = wrfrf_b; off = base - C1; }
            else if (base < C3) { s = Wrfbb; dst = wrfbb_b; off = base - C2; }
            else if (base < C4) { s = Wbbrf; dst = wbbrf_b; off = base - C3; }
            else                { s = Wbbbb; dst = wbbbb_b; off = base - C4; }
            float4 f0 = ((const float4*)(s + off))[0];
            float4 f1 = ((const float4*)(s + off))[1];
            *(short8*)(dst + off) = cvt8v(f0, f1);
        }
    }
}

// ---- new_RF = mish(RF@Wrfrf^T+b1) + mish(mean@Wbbrf^T+b2); also rf2bb slices ----
// EXACT Round-0 structure (proven 48us): 512 blocks x 256 thr; tile 128x64; BK=32;
// 32 dbuf iters; LDP=40; 33.3KB LDS -> 4 blocks/CU. Only change: bf16 inputs,
// no cvt in the staging path (short8 passthrough).
__global__ void __launch_bounds__(256) k_newrf(
    const short* __restrict__ rfb,     // [4096,1024] bf16
    const short* __restrict__ meanb,   // [4096,128]  bf16
    const short* __restrict__ wrfrfb,  // [1024,1024] bf16
    const float* __restrict__ brfrf,
    const short* __restrict__ wbbrfb,  // [1024,128]  bf16
    const float* __restrict__ bbbrf,
    const short* __restrict__ wrfbbb,  // [128,1024]  bf16
    const float* __restrict__ brfbb,
    float* __restrict__ out,           // [4096,1024]
    float* __restrict__ rf2bb)         // [4096,128] fp32 ws
{
    __shared__ short As[2][128 * LDP];
    __shared__ short Bs[2][64 * LDP];
    __shared__ short Ws2[2][16 * LDP];
    int tid = threadIdx.x;
    int wave = tid >> 6, lane = tid & 63;
    int r = lane & 15, quad = lane >> 4;
    int wm = (wave & 1) * 64, wn = (wave >> 1) * 32;
    int mt = blockIdx.x >> 4, nt = blockIdx.x & 15;
    int m0 = mt * 128, n0 = nt * 64;
    bool doP = (nt < 8);

    int arow = tid >> 1, akh = (tid & 1) * 16;
    int brow = tid >> 2, bkq = (tid & 3) * 8;
    int aidx = arow * LDP + akh;
    int bidx = brow * LDP + bkq;
    int widx = (tid >> 2) * LDP + bkq;           // tid<64 only

    const short* aG = rfb    + (size_t)(m0 + arow) * RDIM + akh;
    const short* bG = wrfrfb + (size_t)(n0 + brow) * RDIM + bkq;
    const short* wG = wrfbbb + (size_t)(nt * 16 + (tid >> 2)) * RDIM + bkq; // tid<64

    floatx4 acc1[4][2], acc2[4][2], acc3[4];
    #pragma unroll
    for (int mi = 0; mi < 4; ++mi) {
        acc1[mi][0] = floatx4{0.f,0.f,0.f,0.f}; acc1[mi][1] = acc1[mi][0];
        acc2[mi][0] = acc1[mi][0]; acc2[mi][1] = acc1[mi][0];
        acc3[mi] = acc1[mi][0];
    }
    short8 ra0, ra1, rb0, rw0;
    bool wload = doP && (tid < 64);

    // preload tile0 -> regs -> buf0, then load tile1
    ra0 = ((const short8*)aG)[0]; ra1 = ((const short8*)aG)[1];
    rb0 = ((const short8*)bG)[0];
    if (wload) rw0 = ((const short8*)wG)[0];
    *(short8*)&As[0][aidx]     = ra0;
    *(short8*)&As[0][aidx + 8] = ra1;
    *(short8*)&Bs[0][bidx]     = rb0;
    if (wload) *(short8*)&Ws2[0][widx] = rw0;
    ra0 = ((const short8*)(aG + 32))[0]; ra1 = ((const short8*)(aG + 32))[1];
    rb0 = ((const short8*)(bG + 32))[0];
    if (wload) rw0 = ((const short8*)(wG + 32))[0];
    __syncthreads();

    for (int it = 0; it < 32; ++it) {
        const short* Ac = As[it & 1];
        const short* Bc = Bs[it & 1];
        const short* Wc = Ws2[it & 1];
        short8 af[4];
        #pragma unroll
        for (int mi = 0; mi < 4; ++mi)
            af[mi] = *(const short8*)&Ac[(wm + mi * 16 + r) * LDP + quad * 8];
        short8 bf[2];
        bf[0] = *(const short8*)&Bc[(wn + r) * LDP + quad * 8];
        bf[1] = *(const short8*)&Bc[(wn + 16 + r) * LDP + quad * 8];
        #pragma unroll
        for (int mi = 0; mi < 4; ++mi) {
            acc1[mi][0] = MFMA(af[mi], bf[0], acc1[mi][0]);
            acc1[mi][1] = MFMA(af[mi], bf[1], acc1[mi][1]);
        }
        if (doP && (wave & 2) == 0) {
            short8 b2 = *(const short8*)&Wc[r * LDP + quad * 8];
            #pragma unroll
            for (int mi = 0; mi < 4; ++mi) acc3[mi] = MFMA(af[mi], b2, acc3[mi]);
        }
        if (it < 31) {
            int nb = (it + 1) & 1;
            *(short8*)&As[nb][aidx]     = ra0;
            *(short8*)&As[nb][aidx + 8] = ra1;
            *(short8*)&Bs[nb][bidx]     = rb0;
            if (wload) *(short8*)&Ws2[nb][widx] = rw0;
        }
        if (it < 30) {
            int k = (it + 2) * 32;
            ra0 = ((const short8*)(aG + k))[0]; ra1 = ((const short8*)(aG + k))[1];
            rb0 = ((const short8*)(bG + k))[0];
            if (wload) rw0 = ((const short8*)(wG + k))[0];
        }
        __syncthreads();
    }

    // ---- GEMM2: mean @ Wbbrf^T, K=128 (4 dbuf iters) ----
    const short* a2G = meanb  + (size_t)(m0 + arow) * BDIM + akh;
    const short* b2G = wbbrfb + (size_t)(n0 + brow) * BDIM + bkq;
    ra0 = ((const short8*)a2G)[0]; ra1 = ((const short8*)a2G)[1];
    rb0 = ((const short8*)b2G)[0];
    *(short8*)&As[0][aidx]     = ra0;
    *(short8*)&As[0][aidx + 8] = ra1;
    *(short8*)&Bs[0][bidx]     = rb0;
    ra0 = ((const short8*)(a2G + 32))[0]; ra1 = ((const short8*)(a2G + 32))[1];
    rb0 = ((const short8*)(b2G + 32))[0];
    __syncthreads();
    for (int it = 0; it < 4; ++it) {
        const short* Ac = As[it & 1];
        const short* Bc = Bs[it & 1];
        short8 af[4];
        #pragma unroll
        for (int mi = 0; mi < 4; ++mi)
            af[mi] = *(const short8*)&Ac[(wm + mi * 16 + r) * LDP + quad * 8];
        short8 bf[2];
        bf[0] = *(const short8*)&Bc[(wn + r) * LDP + quad * 8];
        bf[1] = *(const short8*)&Bc[(wn + 16 + r) * LDP + quad * 8];
        #pragma unroll
        for (int mi = 0; mi < 4; ++mi) {
            acc2[mi][0] = MFMA(af[mi], bf[0], acc2[mi][0]);
            acc2[mi][1] = MFMA(af[mi], bf[1], acc2[mi][1]);
        }
        if (it < 3) {
            int nb = (it + 1) & 1;
            *(short8*)&As[nb][aidx]     = ra0;
            *(short8*)&As[nb][aidx + 8] = ra1;
            *(short8*)&Bs[nb][bidx]     = rb0;
        }
        if (it < 2) {
            int k = (it + 2) * 32;
            ra0 = ((const short8*)(a2G + k))[0]; ra1 = ((const short8*)(a2G + k))[1];
            rb0 = ((const short8*)(b2G + k))[0];
        }
        __syncthreads();
    }

    // ---- epilogue ----
    #pragma unroll
    for (int nj = 0; nj < 2; ++nj) {
        int col = n0 + wn + nj * 16 + r;
        float b1 = brfrf[col];
        float b2 = bbbrf[col];
        #pragma unroll
        for (int mi = 0; mi < 4; ++mi) {
            #pragma unroll
            for (int g = 0; g < 4; ++g) {
                int row = m0 + wm + mi * 16 + quad * 4 + g;
                out[(size_t)row * RDIM + col] =
                    mishf(acc1[mi][nj][g] + b1) + mishf(acc2[mi][nj][g] + b2);
            }
        }
    }
    if (doP && (wave & 2) == 0) {
        int col = nt * 16 + r;
        float bs = brfbb[col];
        #pragma unroll
        for (int mi = 0; mi < 4; ++mi) {
            #pragma unroll
            for (int g = 0; g < 4; ++g) {
                int row = m0 + wm + mi * 16 + quad * 4 + g;
                rf2bb[(size_t)row * BDIM + col] = mishf(acc3[mi][g] + bs);
            }
        }
    }
}

// ---------------- new_BB = mish(BB @ W_bbbb^T + b) + rf2bb[b] ----------------
// 1024 blocks x 64-row tiles; A (16KB) + W (32KB) both staged via coalesced gld16
// (pre-swizzled source); 48KB LDS -> 3 blocks/CU; one barrier; 32 MFMAs/wave.
__global__ void __launch_bounds__(256) k_newbb(
    const short* __restrict__ bbb,   // [65536,128] bf16
    const short* __restrict__ wb,    // [128,128]   bf16
    const float* __restrict__ bias,  // [128]
    const float* __restrict__ rf2bb, // [4096,128]  fp32
    float* __restrict__ out)         // [65536,128]
{
    __shared__ alignas(16) short At[64 * 128];
    __shared__ alignas(16) short Wt[128 * 128];
    int tid = threadIdx.x;
    int wave = tid >> 6, lane = tid & 63;
    int r = lane & 15, quad = lane >> 4;
    size_t m0 = (size_t)blockIdx.x * 64;

    int lrow = lane >> 4;     // 0..3
    int lslot = lane & 15;    // 16B slot within 256B row
    // stage W: wave w -> rows w*32 .. w*32+31 (8 issues of 4 rows)
    #pragma unroll
    for (int j = 0; j < 8; ++j) {
        int row = wave * 32 + j * 4 + lrow;
        int col = ((lslot ^ (row & 7)) << 3);   // pre-swizzled source column
        gld16(wb + (size_t)row * BDIM + col, &Wt[(wave * 32 + j * 4) * 128]);
    }
    // stage A: wave w -> rows w*16 .. w*16+15 (4 issues of 4 rows)
    #pragma unroll
    for (int j = 0; j < 4; ++j) {
        int row = wave * 16 + j * 4 + lrow;
        int col = ((lslot ^ (row & 7)) << 3);
        gld16(bbb + (m0 + row) * BDIM + col, &At[(wave * 16 + j * 4) * 128]);
    }

    floatx4 acc[8];
    #pragma unroll
    for (int j = 0; j < 8; ++j) acc[j] = floatx4{0.f,0.f,0.f,0.f};

    // per-wave rows are one batch: rf2bb row = m0/16 + wave
    size_t prow = (m0 >> 4) + wave;

    __syncthreads();   // drains gld16 -> tiles ready

    #pragma unroll
    for (int kc = 0; kc < 4; ++kc) {
        int sw = (((kc << 2) + quad) ^ (r & 7)) << 3;
        short8 a = *(const short8*)&At[(wave * 16 + r) * 128 + sw];
        #pragma unroll
        for (int nj = 0; nj < 8; ++nj) {
            short8 b = *(const short8*)&Wt[(nj * 16 + r) * 128 + sw];
            acc[nj] = MFMA(a, b, acc[nj]);
        }
    }

    #pragma unroll
    for (int nj = 0; nj < 8; ++nj) {
        int col = nj * 16 + r;
        float bs = bias[col];
        float pv = rf2bb[prow * BDIM + col];
        #pragma unroll
        for (int g = 0; g < 4; ++g) {
            size_t row = m0 + wave * 16 + quad * 4 + g;
            out[row * BDIM + col] = mishf(acc[nj][g] + bs) + pv;
        }
    }
}

extern "C" void kernel_launch(void* const* d_in, const int* in_sizes, int n_in,
                              void* d_out, int out_size, void* d_ws, size_t ws_size,
                              hipStream_t stream) {
    const float* BB    = (const float*)d_in[0];
    const float* RF    = (const float*)d_in[1];
    const float* Wrfbb = (const float*)d_in[2];
    const float* brfbb = (const float*)d_in[3];
    const float* Wrfrf = (const float*)d_in[4];
    const float* brfrf = (const float*)d_in[5];
    const float* Wbbrf = (const float*)d_in[6];
    const float* bbbrf = (const float*)d_in[7];
    const float* Wbbbb = (const float*)d_in[8];
    const float* bbbbb = (const float*)d_in[9];

    float* outBB = (float*)d_out;
    float* outRF = outBB + (size_t)NB * NG * BDIM;

    char* w = (char*)d_ws;
    short* mean_b  = (short*)(w);                  // 4096*128*2    = 1,048,576
    short* rf_b    = (short*)(w + 1048576);        // 4096*1024*2   = 8,388,608
    short* wrfrf_b = (short*)(w + 9437184);        // 1024*1024*2   = 2,097,152
    short* wrfbb_b = (short*)(w + 11534336);       // 128*1024*2    =   262,144
    short* wbbrf_b = (short*)(w + 11796480);       // 1024*128*2    =   262,144
    short* wbbbb_b = (short*)(w + 12058624);       // 128*128*2     =    32,768
    short* bb_b    = (short*)(w + 12091392);       // 65536*128*2   = 16,777,216
    float* rf2bb   = (float*)(w + 28868608);       // 4096*128*4    =  2,097,152
    // total ws: 30,965,760 B

    k_prep <<<512 + FLATB, 256, 0, stream>>>(BB, RF, Wrfrf, Wrfbb, Wbbrf, Wbbbb,
                                             bb_b, mean_b, rf_b, wrfrf_b, wrfbb_b,
                                             wbbrf_b, wbbbb_b);
    k_newrf<<<512, 256, 0, stream>>>(rf_b, mean_b, wrfrf_b, brfrf, wbbrf_b, bbbrf,
                                     wrfbb_b, brfbb, outRF, rf2bb);
    k_newbb<<<1024, 256, 0, stream>>>(bb_b, wbbbb_b, bbbbb, rf2bb, outBB);
}